// Round 1
// baseline (778.352 us; speedup 1.0000x reference)
//
#include <hip/hip_runtime.h>

#define IWE_H 480
#define IWE_W 640
#define IWE_HW (IWE_H * IWE_W)
#define FLOW_SCALING 128.0f
#define MAX_TS 1.0f

__global__ void iwe_splat_kernel(const float* __restrict__ ev,    // [B,N,4] (ts,y,x,p)
                                 const float* __restrict__ flow,  // [B,2,H,W] (x-flow ch0, y-flow ch1)
                                 float* __restrict__ out,         // [B,2,H,W] (pos, neg)
                                 int N)
{
    int n = blockIdx.x * blockDim.x + threadIdx.x;
    int b = blockIdx.y;
    if (n >= N) return;

    float4 e = *reinterpret_cast<const float4*>(ev + ((size_t)b * N + n) * 4);
    float ts = e.x, y = e.y, x = e.z, p = e.w;

    const float* fb = flow + (size_t)b * 2 * IWE_HW;
    int lin0 = (int)(y * (float)IWE_W + x);        // exact: < 2^24
    float fx = fb[lin0];                            // channel 0 = x-flow
    float fy = fb[IWE_HW + lin0];                   // channel 1 = y-flow

    float dt = (MAX_TS - ts) * FLOW_SCALING;
    float wy = y + dt * fy;
    float wx = x + dt * fx;

    float ty = floorf(wy), lx = floorf(wx);
    float fyf = wy - ty;                            // in [0,1)
    float fxf = wx - lx;

    // bilinear weights == max(0, 1-|warped-corner|) products (fracs in [0,1))
    float w00 = (1.f - fyf) * (1.f - fxf);          // (ty, lx)
    float w01 = (1.f - fyf) * fxf;                  // (ty, rx)
    float w10 = fyf * (1.f - fxf);                  // (by, lx)
    float w11 = fyf * fxf;                          // (by, rx)

    // bounds masks on the float corner coords (matches reference semantics)
    bool y0 = (ty >= 0.f)       && (ty < (float)IWE_H);
    bool y1 = (ty + 1.f >= 0.f) && (ty + 1.f < (float)IWE_H);
    bool x0 = (lx >= 0.f)       && (lx < (float)IWE_W);
    bool x1 = (lx + 1.f >= 0.f) && (lx + 1.f < (float)IWE_W);

    int iy = (int)ty, ix = (int)lx;
    // polarity plane: pol_mask = [p>0, !(p>0)] one-hot, so pick plane from p
    float* plane = out + ((size_t)b * 2 + (p > 0.f ? 0 : 1)) * IWE_HW;

    if (y0 && x0 && w00 != 0.f) atomicAdd(plane + iy * IWE_W + ix,           w00);
    if (y0 && x1 && w01 != 0.f) atomicAdd(plane + iy * IWE_W + ix + 1,       w01);
    if (y1 && x0 && w10 != 0.f) atomicAdd(plane + (iy + 1) * IWE_W + ix,     w10);
    if (y1 && x1 && w11 != 0.f) atomicAdd(plane + (iy + 1) * IWE_W + ix + 1, w11);
}

extern "C" void kernel_launch(void* const* d_in, const int* in_sizes, int n_in,
                              void* d_out, int out_size, void* d_ws, size_t ws_size,
                              hipStream_t stream) {
    const float* ev   = (const float*)d_in[0];   // [B,N,4]
    const float* flow = (const float*)d_in[1];   // [B,2,H,W]
    // d_in[2] = pol_mask [B,N,2] — redundant with ev[...,3], not read
    float* out = (float*)d_out;                  // [B,2,H,W]

    int B = in_sizes[1] / (2 * IWE_HW);          // flow elements / (2*H*W)
    int N = in_sizes[0] / (4 * B);

    hipMemsetAsync(d_out, 0, (size_t)out_size * sizeof(float), stream);

    dim3 block(256);
    dim3 grid((N + 255) / 256, B);
    iwe_splat_kernel<<<grid, block, 0, stream>>>(ev, flow, out, N);
}